// Round 13
// baseline (201.223 us; speedup 1.0000x reference)
//
#include <hip/hip_runtime.h>
#include <hip/hip_fp16.h>

#define IMG_W 2048
#define IMG_H 2048
#define HALF  10          // max_coc // 2
#define TILE  64          // 64x64 output tile
#define HLO   84          // halo dim (64 + 2*10)
#define SLOTS 86          // padded row stride in uint2 (ty-stride = 688 dw = 16 mod 32)

// Separable LUT, one 55-dword plane per k (ODD stride -> injective k->bank):
//   dwords  0..25 : wy entries; e = pack2(wy(e-12), wy(e-13))
//                   (row r0,r1 at src row aa -> e=aa+2; r2,r3 -> e=aa)
//   dwords 26..39 : wx pairs   h: pack2(wx(2h-13), wx(2h-12))  (pos 2h,2h+1)
//   dwords 40..53 : wx shifted j: pack2(wx(2j-12), wx(2j-11))  (pos 2j+1,2j+2)
//   dword  54     : pad
#define L_KSD 55
#define L_KSB 220              // byte plane stride (k*220 fits u16)
#define L_NDW (22 * L_KSD)     // 1210 dwords = 4840 B

__device__ __forceinline__ __half2 h2(uint u)  { union { uint a; __half2 b; } c; c.a = u; return c.b; }
__device__ __forceinline__ uint pack2(float a, float b) {
    return (uint)__half_as_ushort(__float2half(a)) |
           ((uint)__half_as_ushort(__float2half(b)) << 16);
}
// weight factors: w(k,oy,ox) = wyv(k,oy) * wxv(k,ox); norm folded into wy
__device__ __forceinline__ float wyv(int k, int oy) {
    int a = abs(oy), hk = k >> 1;
    if (a > hk) return 0.f;
    if (k <= 1) return 1.f;
    float kk = (float)(k * k);
    return expf(-(float)(oy * oy) * 18.f / kk) * 5.7295780f / kk;
}
__device__ __forceinline__ float wxv(int k, int ox) {
    int a = abs(ox), hk = k >> 1;
    if (a > hk) return 0.f;
    if (k <= 1) return 1.f;
    float kk = (float)(k * k);
    return expf(-(float)(ox * ox) * 18.f / kk);
}

// VOP3P with explicit op_sel broadcasts (zero splat instructions):
#define FMA_LO(acc, px, wgt) \
    asm("v_pk_fma_f16 %0, %1, %2, %0 op_sel:[0,0,0] op_sel_hi:[0,1,1]" \
        : "+v"(acc) : "v"(px), "v"(wgt))
#define FMA_HI(acc, px, wgt) \
    asm("v_pk_fma_f16 %0, %1, %2, %0 op_sel:[1,0,0] op_sel_hi:[1,1,1]" \
        : "+v"(acc) : "v"(px), "v"(wgt))
#define MUL_WYLO(d, wx2, wy2) \
    asm("v_pk_mul_f16 %0, %1, %2 op_sel:[0,0] op_sel_hi:[1,0]" \
        : "=v"(d) : "v"(wx2), "v"(wy2))
#define MUL_WYHI(d, wx2, wy2) \
    asm("v_pk_mul_f16 %0, %1, %2 op_sel:[0,1] op_sel_hi:[1,1]" \
        : "=v"(d) : "v"(wx2), "v"(wy2))

__global__ __launch_bounds__(256, 2)
void defocus_44b_kernel(const float* __restrict__ img,
                        const int* __restrict__ ks,
                        float* __restrict__ out)
{
    __shared__ uint  lutw[L_NDW + 2];        // 4848 B
    __shared__ uint2 tile[HLO * SLOTS];      // 57792 B  (total ~62.7 KB -> 2 blocks/CU)

    const int tid = threadIdx.x;
    const int X0 = blockIdx.x * TILE;
    const int Y0 = blockIdx.y * TILE;

    // ---- build separable LUT ----
    for (int i = tid; i < L_NDW; i += 256) {
        int k = i / L_KSD;
        int d = i - k * L_KSD;
        float lo = 0.f, hi = 0.f;
        if (d < 26) {                       // wy entry e=d: (wy(e-12), wy(e-13))
            lo = wyv(k, d - 12);
            hi = wyv(k, d - 13);
        } else if (d < 40) {                // wx pair, pos (2h, 2h+1)
            int j = d - 26;
            lo = wxv(k, 2 * j - 13);
            hi = wxv(k, 2 * j - 12);
        } else if (d < 54) {                // shifted wx pair, pos (2j+1, 2j+2)
            int j = d - 40;
            lo = wxv(k, 2 * j - 12);
            hi = wxv(k, 2 * j - 11);
        }
        lutw[i] = pack2(lo, hi);
    }

    // ---- stage 84x84 halo tile, phase-major cols, padded row stride 86 ----
    for (int i = tid; i < HLO * HLO; i += 256) {
        int r = i / HLO;
        int c = i - r * HLO;
        int gy = Y0 - HALF + r;
        int gx = X0 - HALF + c;
        float fr = 0.f, fg = 0.f, fb = 0.f;
        uint koffB = 0;
        if (gy >= 0 && gy < IMG_H && gx >= 0 && gx < IMG_W) {
            int p = gy * IMG_W + gx;
            fr = img[p * 3 + 0];
            fg = img[p * 3 + 1];
            fb = img[p * 3 + 2];
            koffB = (uint)(ks[p] * L_KSB);
        }
        uint2 v;
        v.x = pack2(fr, fg);
        v.y = koffB | ((uint)__half_as_ushort(__float2half(fb)) << 16);
        tile[r * SLOTS + (c & 3) * 21 + (c >> 2)] = v;
    }
    __syncthreads();

    const int tx = tid & 15;       // 16 thread-cols
    const int ty = tid >> 4;       // 16 thread-rows
    const int colbase = tx * 4;
    const int rowbase = ty * 4;
    const int pxbase  = rowbase * SLOTS + tx;

    // f16 pair accumulators: A32[r][ch]=(col3,col2), A10[r][ch]=(col1,col0)
    uint A32[4][3] = {}, A10[4][3] = {};
    float mc[4][4][3];              // f32 masters [r][col][ch]
    #pragma unroll
    for (int r = 0; r < 4; ++r)
        #pragma unroll
        for (int c = 0; c < 3; ++c)
            mc[r][0][c] = mc[r][1][c] = mc[r][2][c] = mc[r][3][c] = 0.f;

#define PIDX(b) (((b) & 3) * 21 + ((b) >> 2))

#define PXG(buf, B0)                                   \
    { buf[0] = tile[pxrow + PIDX((B0) + 0)];           \
      buf[1] = tile[pxrow + PIDX((B0) + 1)];           \
      buf[2] = tile[pxrow + PIDX((B0) + 2)];           \
      buf[3] = tile[pxrow + PIDX((B0) + 3)];           \
      buf[4] = tile[pxrow + PIDX((B0) + 4)];           \
      buf[5] = tile[pxrow + PIDX((B0) + 5)];           \
      buf[6] = tile[pxrow + PIDX((B0) + 6)];           \
      buf[7] = tile[pxrow + PIDX((B0) + 7)]; }

    // weight fetch for one tap: q = {wyA(e=aa+2), wyB(e=aa), w32, w10}
#define WLD1(q, pvv, aa, b)                                                        \
    { const uint* wp = (const uint*)((const char*)lutw + ((pvv).y & 0xffffu));     \
      (q).x = wp[(aa) + 2];                                                        \
      (q).y = wp[(aa)];                                                            \
      (q).z = (((b) & 1) == 0) ? wp[26 + ((b) >> 1)] : wp[40 + (((b) - 1) >> 1)];  \
      (q).w = (((b) & 1) == 0) ? wp[27 + ((b) >> 1)] : wp[41 + (((b) - 1) >> 1)]; }

#define WG(wv, buf, aa, B0)                 \
    { WLD1(wv[0], buf[0], aa, (B0) + 0);    \
      WLD1(wv[1], buf[1], aa, (B0) + 1);    \
      WLD1(wv[2], buf[2], aa, (B0) + 2);    \
      WLD1(wv[3], buf[3], aa, (B0) + 3);    \
      WLD1(wv[4], buf[4], aa, (B0) + 4);    \
      WLD1(wv[5], buf[5], aa, (B0) + 5);    \
      WLD1(wv[6], buf[6], aa, (B0) + 6);    \
      WLD1(wv[7], buf[7], aa, (B0) + 7); }

#define FMA1(pvv, q)                                                   \
    { uint Wr[4], Vr[4];                                               \
      MUL_WYLO(Wr[0], (q).z, (q).x); MUL_WYHI(Wr[1], (q).z, (q).x);    \
      MUL_WYLO(Wr[2], (q).z, (q).y); MUL_WYHI(Wr[3], (q).z, (q).y);    \
      MUL_WYLO(Vr[0], (q).w, (q).x); MUL_WYHI(Vr[1], (q).w, (q).x);    \
      MUL_WYLO(Vr[2], (q).w, (q).y); MUL_WYHI(Vr[3], (q).w, (q).y);    \
      _Pragma("unroll")                                                \
      for (int r = 0; r < 4; ++r) {                                    \
          FMA_LO(A32[r][0], (pvv).x, Wr[r]);                           \
          FMA_HI(A32[r][1], (pvv).x, Wr[r]);                           \
          FMA_HI(A32[r][2], (pvv).y, Wr[r]);                           \
          FMA_LO(A10[r][0], (pvv).x, Vr[r]);                           \
          FMA_HI(A10[r][1], (pvv).x, Vr[r]);                           \
          FMA_HI(A10[r][2], (pvv).y, Vr[r]);                           \
      } }

#define FMAG(buf, wv)          \
    { FMA1(buf[0], wv[0]);     \
      FMA1(buf[1], wv[1]);     \
      FMA1(buf[2], wv[2]);     \
      FMA1(buf[3], wv[3]);     \
      FMA1(buf[4], wv[4]);     \
      FMA1(buf[5], wv[5]);     \
      FMA1(buf[6], wv[6]);     \
      FMA1(buf[7], wv[7]); }

    // One source row: 3 groups of 8 taps, px prefetched ahead, batched weights
#define ROW(aa)                                \
    { const int pxrow = pxbase + (aa) * SLOTS; \
      uint2 p0[8], p1[8];                      \
      uint4 wv[8];                             \
      PXG(p0, 0);                              \
      PXG(p1, 8);                              \
      WG(wv, p0, (aa), 0);                     \
      FMAG(p0, wv);                            \
      PXG(p0, 16);                             \
      WG(wv, p1, (aa), 8);                     \
      FMAG(p1, wv);                            \
      WG(wv, p0, (aa), 16);                    \
      FMAG(p0, wv); }

#define FLUSH()                                                        \
    { _Pragma("unroll")                                                \
      for (int r = 0; r < 4; ++r) {                                    \
          _Pragma("unroll")                                            \
          for (int c = 0; c < 3; ++c) {                                \
              float2 f3 = __half22float2(h2(A32[r][c]));               \
              float2 f1 = __half22float2(h2(A10[r][c]));               \
              mc[r][3][c] += f3.x; mc[r][2][c] += f3.y;                \
              mc[r][1][c] += f1.x; mc[r][0][c] += f1.y;                \
              A32[r][c] = 0; A10[r][c] = 0;                            \
          }                                                            \
      } }

    // 24 source rows, flush f16 partials (<=48 taps) every 2 rows
    #pragma unroll 1
    for (int ap = 0; ap < 12; ++ap) {
        ROW(2 * ap);
        ROW(2 * ap + 1);
        FLUSH();
    }

    // ---- store ----
    #pragma unroll
    for (int r = 0; r < 4; ++r) {
        int gy = Y0 + rowbase + r;
        #pragma unroll
        for (int m = 0; m < 4; ++m) {
            int gx = X0 + colbase + m;
            int o = (gy * IMG_W + gx) * 3;
            out[o + 0] = mc[r][m][0];
            out[o + 1] = mc[r][m][1];
            out[o + 2] = mc[r][m][2];
        }
    }
#undef ROW
#undef FLUSH
#undef PXG
#undef WG
#undef FMAG
#undef FMA1
#undef WLD1
#undef PIDX
}

extern "C" void kernel_launch(void* const* d_in, const int* in_sizes, int n_in,
                              void* d_out, int out_size, void* d_ws, size_t ws_size,
                              hipStream_t stream) {
    const float* img = (const float*)d_in[0];
    const int*   ks  = (const int*)d_in[1];
    float* out = (float*)d_out;

    dim3 grid(IMG_W / TILE, IMG_H / TILE);   // 32 x 32
    dim3 block(256);
    defocus_44b_kernel<<<grid, block, 0, stream>>>(img, ks, out);
}